// Round 1
// baseline (487.564 us; speedup 1.0000x reference)
//
#include <hip/hip_runtime.h>

// Problem constants
// B=32, CI=64, CO=64, H=128, W=128, E=5, T=10, 5x5 SAME conv.
// d_out = y[32*64*128*128] f32 ++ task_id[32] (as float).

using bf16x8   = __attribute__((ext_vector_type(8)))  __bf16;
using floatx16 = __attribute__((ext_vector_type(16))) float;

// ws layout:
//   xt : [32][128][8 cc][132 wp][8 ci] bf16  = 69,206,016 B   (NHWC-ish, width-padded+zeroed)
//   wk : [10 t][25 tap][64 co][64 ci] bf16   =  2,048,000 B
// total 71,254,016 B required in d_ws.
#define XT_SHORTS 34603008   // 32*128*8448
#define WK_OFFSET_BYTES 69206016ull

static __device__ __forceinline__ unsigned short f2bf(float f) {
    unsigned int u = __float_as_uint(f);
    u += 0x7FFFu + ((u >> 16) & 1u);          // round-to-nearest-even (finite inputs)
    return (unsigned short)(u >> 16);
}

static __device__ __forceinline__ floatx16 mfma16(bf16x8 a, bf16x8 b, floatx16 c) {
    return __builtin_amdgcn_mfma_f32_32x32x16_bf16(a, b, c, 0, 0, 0);
}

// ---------------------------------------------------------------------------
// Kernel 1: gate softmax + per-task 5x5 kernel synthesis (+ task_id output)
// grid = 10 tasks * 16 chunks, block = 256
// wk[t][tap][co][ci], ci contiguous (A-fragment needs 8 consecutive ci).
// ---------------------------------------------------------------------------
__global__ __launch_bounds__(256) void prep_kernel(
    const float* __restrict__ gate_w, const float* __restrict__ gate_b,
    const float* __restrict__ w5, const float* __restrict__ w3,
    const float* __restrict__ w1, const float* __restrict__ wavg3,
    const float* __restrict__ wavg5, const int* __restrict__ task_id,
    unsigned short* __restrict__ wk, float* __restrict__ out_task)
{
    const int t = blockIdx.x >> 4;         // 0..9
    const int chunk = blockIdx.x & 15;     // 0..15
    const int tid = threadIdx.x;

    __shared__ float g[5][64];
    if (tid < 64) {
        float l[5];
        float m = -1e30f;
        #pragma unroll
        for (int e = 0; e < 5; ++e) {
            l[e] = gate_w[(e * 64 + tid) * 10 + t] + gate_b[e * 64 + tid];
            m = fmaxf(m, l[e]);
        }
        float s = 0.f;
        #pragma unroll
        for (int e = 0; e < 5; ++e) { l[e] = expf(l[e] - m); s += l[e]; }
        float inv = 1.f / s;
        #pragma unroll
        for (int e = 0; e < 5; ++e) g[e][tid] = l[e] * inv;
    }
    __syncthreads();

    // 102,400 elems per task; 6,400 per chunk; 25 per thread
    for (int it = 0; it < 25; ++it) {
        int idx = chunk * 6400 + it * 256 + tid;
        int ci  = idx & 63;
        int o   = (idx >> 6) & 63;
        int tap = idx >> 12;               // 0..24
        int ky = tap / 5, kx = tap - ky * 5;

        float v = g[0][o] * w5[(o * 64 + ci) * 25 + tap];
        bool in3 = (ky >= 1 && ky <= 3 && kx >= 1 && kx <= 3);
        if (in3) {
            v += g[1][o] * w3[(o * 64 + ci) * 9 + (ky - 1) * 3 + (kx - 1)];
            v += g[3][o] * wavg3[o * 64 + ci] * (1.f / 9.f);
        }
        if (ky == 2 && kx == 2) v += g[2][o] * w1[o * 64 + ci];
        v += g[4][o] * wavg5[o * 64 + ci] * (1.f / 25.f);

        wk[(t * 25 + tap) * 4096 + o * 64 + ci] = f2bf(v);
    }

    if (blockIdx.x == 0 && tid < 32) out_task[tid] = (float)task_id[tid];
}

// ---------------------------------------------------------------------------
// Kernel 2: x NCHW f32 -> xt [b][h][cc][wp:132][8ci] bf16, width borders zeroed
// grid = 32*128 (one row per WG), block = 256
// ---------------------------------------------------------------------------
__global__ __launch_bounds__(256) void transform_kernel(
    const float* __restrict__ x, unsigned short* __restrict__ xt)
{
    const int bh = blockIdx.x;             // b*128 + h
    const int b = bh >> 7, h = bh & 127;

    for (int i = threadIdx.x; i < 1056; i += 256) {   // 8 cc * 132 wp blocks
        int cc = i / 132;
        int wp = i - cc * 132;
        unsigned int pk[4] = {0u, 0u, 0u, 0u};
        if (wp >= 2 && wp < 130) {
            int w = wp - 2;
            const float* xp = x + (((b * 64 + cc * 8) * 128 + h) * 128 + w);
            #pragma unroll
            for (int j = 0; j < 4; ++j) {
                unsigned short lo = f2bf(xp[(2 * j)     * 16384]);
                unsigned short hi = f2bf(xp[(2 * j + 1) * 16384]);
                pk[j] = (unsigned int)lo | ((unsigned int)hi << 16);
            }
        }
        uint4* dst = (uint4*)(xt + (size_t)bh * 8448 + (size_t)i * 8);
        *dst = make_uint4(pk[0], pk[1], pk[2], pk[3]);
    }
}

// ---------------------------------------------------------------------------
// Kernel 3: MFMA conv. WG = 256 thr (4 waves), tile = 64co x (2 rows x 128 w).
// LDS: 6 rows x 4 cc x 132 wp x 8 ci bf16 = 50,688 B (one 32-ci half at a time)
// grid = 32 b * 64 htiles
// ---------------------------------------------------------------------------
__global__ __launch_bounds__(256, 2) void conv_kernel(
    const unsigned short* __restrict__ xt, const unsigned short* __restrict__ wk,
    const int* __restrict__ task_id, float* __restrict__ out)
{
    __shared__ unsigned short lds[25344];  // 3168 blocks * 8 shorts

    const int blk = blockIdx.x;
    const int b  = blk >> 6;
    const int ht = blk & 63;
    const int h0 = ht * 2;
    const int t  = task_id[b];

    const int tid  = threadIdx.x;
    const int lane = tid & 63;
    const int wave = tid >> 6;
    const int lane31 = lane & 31;
    const int laneh  = lane >> 5;

    // per-wave pos tiles: pt0 = wave*2, pt1 = wave*2+1  (pt>>2 = out row, pt&3 = w tile)
    const int pt0 = wave * 2, pt1 = pt0 + 1;
    const int r_base0 = pt0 >> 2, r_base1 = pt1 >> 2;
    const int wb0 = (pt0 & 3) * 32 + lane31;
    const int wb1 = (pt1 & 3) * 32 + lane31;

    floatx16 acc[2][2];
    #pragma unroll
    for (int c = 0; c < 2; ++c)
        #pragma unroll
        for (int p = 0; p < 2; ++p)
            #pragma unroll
            for (int r = 0; r < 16; ++r) acc[c][p][r] = 0.f;

    const unsigned short* wkt = wk + t * 102400;   // [25 tap][64 co][64 ci]

    for (int half = 0; half < 2; ++half) {
        __syncthreads();
        // stage 6 rows (h0-2 .. h0+3) of 4 cc-planes; OOB rows -> zeros
        for (int i = tid; i < 3168; i += 256) {
            int r = i / 528;
            int rem = i - r * 528;
            int h = h0 - 2 + r;
            uint4 v = make_uint4(0u, 0u, 0u, 0u);
            if (h >= 0 && h < 128)
                v = *(const uint4*)(xt + (size_t)(b * 128 + h) * 8448
                                       + (size_t)half * 4224 + (size_t)rem * 8);
            *(uint4*)(lds + i * 8) = v;
        }
        __syncthreads();

        for (int ky = 0; ky < 5; ++ky) {
            #pragma unroll
            for (int kx = 0; kx < 5; ++kx) {
                #pragma unroll
                for (int kc = 0; kc < 2; ++kc) {
                    // A fragments (weights): k = ci within this 16-chunk
                    int ci0 = half * 32 + kc * 16 + laneh * 8;
                    const unsigned short* ap =
                        wkt + (ky * 5 + kx) * 4096 + ci0;
                    bf16x8 a0 = *(const bf16x8*)(ap + lane31 * 64);
                    bf16x8 a1 = *(const bf16x8*)(ap + (lane31 + 32) * 64);

                    // B fragments (activations) from LDS
                    int cc = kc * 2 + laneh;   // 0..3 within staged half
                    int o0 = (((r_base0 + ky) * 4 + cc) * 132 + wb0 + kx) * 8;
                    int o1 = (((r_base1 + ky) * 4 + cc) * 132 + wb1 + kx) * 8;
                    bf16x8 b0 = *(const bf16x8*)(lds + o0);
                    bf16x8 b1 = *(const bf16x8*)(lds + o1);

                    acc[0][0] = mfma16(a0, b0, acc[0][0]);
                    acc[0][1] = mfma16(a0, b1, acc[0][1]);
                    acc[1][0] = mfma16(a1, b0, acc[1][0]);
                    acc[1][1] = mfma16(a1, b1, acc[1][1]);
                }
            }
        }
    }

    // Epilogue: C/D layout (32x32): col = lane&31, row = (reg&3) + 8*(reg>>2) + 4*(lane>>5)
    #pragma unroll
    for (int c = 0; c < 2; ++c) {
        #pragma unroll
        for (int p = 0; p < 2; ++p) {
            int pt = wave * 2 + p;
            int h = h0 + (pt >> 2);
            int w = (pt & 3) * 32 + lane31;
            #pragma unroll
            for (int reg = 0; reg < 16; ++reg) {
                int co = c * 32 + (reg & 3) + 8 * (reg >> 2) + 4 * laneh;
                out[((size_t)(b * 64 + co) * 128 + h) * 128 + w] = acc[c][p][reg];
            }
        }
    }
}

// ---------------------------------------------------------------------------
extern "C" void kernel_launch(void* const* d_in, const int* in_sizes, int n_in,
                              void* d_out, int out_size, void* d_ws, size_t ws_size,
                              hipStream_t stream) {
    const float* x       = (const float*)d_in[0];
    const int*   task_id = (const int*)  d_in[1];
    const float* gate_w  = (const float*)d_in[2];
    const float* gate_b  = (const float*)d_in[3];
    const float* w5      = (const float*)d_in[4];
    const float* w3      = (const float*)d_in[5];
    const float* w1      = (const float*)d_in[6];
    const float* wavg3   = (const float*)d_in[7];
    const float* wavg5   = (const float*)d_in[8];

    float* out = (float*)d_out;
    float* out_task = out + 32 * 64 * 128 * 128;   // second tuple element

    unsigned short* xt = (unsigned short*)d_ws;
    unsigned short* wk = (unsigned short*)((char*)d_ws + WK_OFFSET_BYTES);
    // requires ws_size >= 71,254,016 bytes

    prep_kernel<<<dim3(160), dim3(256), 0, stream>>>(
        gate_w, gate_b, w5, w3, w1, wavg3, wavg5, task_id, wk, out_task);
    transform_kernel<<<dim3(32 * 128), dim3(256), 0, stream>>>(x, xt);
    conv_kernel<<<dim3(32 * 64), dim3(256), 0, stream>>>(xt, wk, task_id, out);
}

// Round 3
// 412.276 us; speedup vs baseline: 1.1826x; 1.1826x over previous
//
#include <hip/hip_runtime.h>

// Problem constants
// B=32, CI=64, CO=64, H=128, W=128, E=5, T=10, 5x5 SAME conv.
// d_out = y[32*64*128*128] f32 ++ task_id[32] (as float).

using bf16x8   = __attribute__((ext_vector_type(8)))  __bf16;
using floatx16 = __attribute__((ext_vector_type(16))) float;

// ws layout:
//   xt : [32][128][8 cc][132 wp][8 ci] bf16  = 69,206,016 B   (NHWC-ish, width-padded+zeroed)
//   wk : [10 t][25 tap][64 co][64 ci] bf16   =  2,048,000 B
// total 71,254,016 B required in d_ws.
#define WK_OFFSET_BYTES 69206016ull

static __device__ __forceinline__ unsigned short f2bf(float f) {
    unsigned int u = __float_as_uint(f);
    u += 0x7FFFu + ((u >> 16) & 1u);          // round-to-nearest-even (finite inputs)
    return (unsigned short)(u >> 16);
}

static __device__ __forceinline__ floatx16 mfma16(bf16x8 a, bf16x8 b, floatx16 c) {
    return __builtin_amdgcn_mfma_f32_32x32x16_bf16(a, b, c, 0, 0, 0);
}

// ---------------------------------------------------------------------------
// Kernel 1: gate softmax + per-task 5x5 kernel synthesis (+ task_id output)
// grid = 10 tasks * 16 chunks, block = 256
// wk[t][tap][co][ci], ci contiguous (A-fragment needs 8 consecutive ci).
// ---------------------------------------------------------------------------
__global__ __launch_bounds__(256) void prep_kernel(
    const float* __restrict__ gate_w, const float* __restrict__ gate_b,
    const float* __restrict__ w5, const float* __restrict__ w3,
    const float* __restrict__ w1, const float* __restrict__ wavg3,
    const float* __restrict__ wavg5, const int* __restrict__ task_id,
    unsigned short* __restrict__ wk, float* __restrict__ out_task)
{
    const int t = blockIdx.x >> 4;         // 0..9
    const int chunk = blockIdx.x & 15;     // 0..15
    const int tid = threadIdx.x;

    __shared__ float g[5][64];
    if (tid < 64) {
        float l[5];
        float m = -1e30f;
        #pragma unroll
        for (int e = 0; e < 5; ++e) {
            l[e] = gate_w[(e * 64 + tid) * 10 + t] + gate_b[e * 64 + tid];
            m = fmaxf(m, l[e]);
        }
        float s = 0.f;
        #pragma unroll
        for (int e = 0; e < 5; ++e) { l[e] = expf(l[e] - m); s += l[e]; }
        float inv = 1.f / s;
        #pragma unroll
        for (int e = 0; e < 5; ++e) g[e][tid] = l[e] * inv;
    }
    __syncthreads();

    // 102,400 elems per task; 6,400 per chunk; 25 per thread
    for (int it = 0; it < 25; ++it) {
        int idx = chunk * 6400 + it * 256 + tid;
        int ci  = idx & 63;
        int o   = (idx >> 6) & 63;
        int tap = idx >> 12;               // 0..24
        int ky = tap / 5, kx = tap - ky * 5;

        float v = g[0][o] * w5[(o * 64 + ci) * 25 + tap];
        bool in3 = (ky >= 1 && ky <= 3 && kx >= 1 && kx <= 3);
        if (in3) {
            v += g[1][o] * w3[(o * 64 + ci) * 9 + (ky - 1) * 3 + (kx - 1)];
            v += g[3][o] * wavg3[o * 64 + ci] * (1.f / 9.f);
        }
        if (ky == 2 && kx == 2) v += g[2][o] * w1[o * 64 + ci];
        v += g[4][o] * wavg5[o * 64 + ci] * (1.f / 25.f);

        wk[(t * 25 + tap) * 4096 + o * 64 + ci] = f2bf(v);
    }

    if (blockIdx.x == 0 && tid < 32) out_task[tid] = (float)task_id[tid];
}

// ---------------------------------------------------------------------------
// Kernel 2: x NCHW f32 -> xt [b][h][cc][wp:132][8ci] bf16, width borders zeroed
// grid = 32*128 (one row per WG), block = 256
// ---------------------------------------------------------------------------
__global__ __launch_bounds__(256) void transform_kernel(
    const float* __restrict__ x, unsigned short* __restrict__ xt)
{
    const int bh = blockIdx.x;             // b*128 + h
    const int b = bh >> 7, h = bh & 127;

    for (int i = threadIdx.x; i < 1056; i += 256) {   // 8 cc * 132 wp blocks
        int cc = i / 132;
        int wp = i - cc * 132;
        unsigned int pk[4] = {0u, 0u, 0u, 0u};
        if (wp >= 2 && wp < 130) {
            int w = wp - 2;
            const float* xp = x + (((b * 64 + cc * 8) * 128 + h) * 128 + w);
            #pragma unroll
            for (int j = 0; j < 4; ++j) {
                unsigned short lo = f2bf(xp[(2 * j)     * 16384]);
                unsigned short hi = f2bf(xp[(2 * j + 1) * 16384]);
                pk[j] = (unsigned int)lo | ((unsigned int)hi << 16);
            }
        }
        uint4* dst = (uint4*)(xt + (size_t)bh * 8448 + (size_t)i * 8);
        *dst = make_uint4(pk[0], pk[1], pk[2], pk[3]);
    }
}

// ---------------------------------------------------------------------------
// Kernel 3: MFMA conv, restructured for ILP.
// WG = 256 thr (4 waves), tile = 64co x (4 rows x 128 w).
// Each wave: one output row, 2 co-tiles x 4 pos-tiles = 8 accumulators.
// K split into 4 quarters of 16 ci; LDS stages 8 input rows x 16 ci:
//   [8 r][2 cc][132 wp][8 ci] bf16 = 33,792 B
// grid = 32 b * 32 htiles
// ---------------------------------------------------------------------------
__global__ __launch_bounds__(256, 2) void conv_kernel(
    const unsigned short* __restrict__ xt, const unsigned short* __restrict__ wk,
    const int* __restrict__ task_id, float* __restrict__ out)
{
    __shared__ unsigned short lds[16896];  // 2112 uint4 blocks

    const int blk = blockIdx.x;
    const int b  = blk >> 5;
    const int ht = blk & 31;
    const int h0 = ht * 4;
    const int t  = task_id[b];

    const int tid  = threadIdx.x;
    const int lane = tid & 63;
    const int wave = tid >> 6;             // = output row offset 0..3
    const int lane31 = lane & 31;
    const int laneh  = lane >> 5;

    floatx16 acc[2][4];
    #pragma unroll
    for (int c = 0; c < 2; ++c)
        #pragma unroll
        for (int p = 0; p < 4; ++p)
            #pragma unroll
            for (int r = 0; r < 16; ++r) acc[c][p][r] = 0.f;

    const unsigned short* wkt = wk + t * 102400;   // [25 tap][64 co][64 ci]
    const size_t xrow = (size_t)(b * 128) * 8448;

    for (int q = 0; q < 4; ++q) {
        __syncthreads();
        // stage 8 rows (h0-2 .. h0+5) of 2 cc-planes (16 ci); OOB rows -> zeros
        for (int i = tid; i < 2112; i += 256) {
            int r = i / 264;               // 0..7
            int rem = i - r * 264;         // 0..263 (uint4 within row)
            int h = h0 - 2 + r;
            uint4 v = make_uint4(0u, 0u, 0u, 0u);
            if (h >= 0 && h < 128)
                v = *(const uint4*)(xt + xrow + (size_t)h * 8448
                                       + (size_t)q * 2112 + (size_t)rem * 8);
            *(uint4*)(lds + i * 8) = v;
        }
        __syncthreads();

        for (int ky = 0; ky < 5; ++ky) {
            // staged row index for this wave's output row: wave + ky (0..7)
            const unsigned short* lrow = lds + (wave + ky) * 2112 + laneh * 1056;
            const unsigned short* wrow = wkt + (ky * 5) * 4096 + q * 16 + laneh * 8;
            #pragma unroll
            for (int kx = 0; kx < 5; ++kx) {
                const unsigned short* ap = wrow + kx * 4096;
                bf16x8 a0 = *(const bf16x8*)(ap + lane31 * 64);
                bf16x8 a1 = *(const bf16x8*)(ap + (lane31 + 32) * 64);

                bf16x8 bb[4];
                #pragma unroll
                for (int p = 0; p < 4; ++p)
                    bb[p] = *(const bf16x8*)(lrow + (p * 32 + lane31 + kx) * 8);

                #pragma unroll
                for (int p = 0; p < 4; ++p) {
                    acc[0][p] = mfma16(a0, bb[p], acc[0][p]);
                    acc[1][p] = mfma16(a1, bb[p], acc[1][p]);
                }
            }
        }
    }

    // Epilogue: C/D layout (32x32): col = lane&31, row = (reg&3) + 8*(reg>>2) + 4*(lane>>5)
    const int h = h0 + wave;
    #pragma unroll
    for (int c = 0; c < 2; ++c) {
        #pragma unroll
        for (int p = 0; p < 4; ++p) {
            int w = p * 32 + lane31;
            #pragma unroll
            for (int reg = 0; reg < 16; ++reg) {
                int co = c * 32 + (reg & 3) + 8 * (reg >> 2) + 4 * laneh;
                out[((size_t)(b * 64 + co) * 128 + h) * 128 + w] = acc[c][p][reg];
            }
        }
    }
}

// ---------------------------------------------------------------------------
extern "C" void kernel_launch(void* const* d_in, const int* in_sizes, int n_in,
                              void* d_out, int out_size, void* d_ws, size_t ws_size,
                              hipStream_t stream) {
    const float* x       = (const float*)d_in[0];
    const int*   task_id = (const int*)  d_in[1];
    const float* gate_w  = (const float*)d_in[2];
    const float* gate_b  = (const float*)d_in[3];
    const float* w5      = (const float*)d_in[4];
    const float* w3      = (const float*)d_in[5];
    const float* w1      = (const float*)d_in[6];
    const float* wavg3   = (const float*)d_in[7];
    const float* wavg5   = (const float*)d_in[8];

    float* out = (float*)d_out;
    float* out_task = out + 32 * 64 * 128 * 128;   // second tuple element

    unsigned short* xt = (unsigned short*)d_ws;
    unsigned short* wk = (unsigned short*)((char*)d_ws + WK_OFFSET_BYTES);
    // requires ws_size >= 71,254,016 bytes

    prep_kernel<<<dim3(160), dim3(256), 0, stream>>>(
        gate_w, gate_b, w5, w3, w1, wavg3, wavg5, task_id, wk, out_task);
    transform_kernel<<<dim3(32 * 128), dim3(256), 0, stream>>>(x, xt);
    conv_kernel<<<dim3(32 * 32), dim3(256), 0, stream>>>(xt, wk, task_id, out);
}